// Round 4
// baseline (148.658 us; speedup 1.0000x reference)
//
#include <hip/hip_runtime.h>

using f32x4  = __attribute__((ext_vector_type(4))) float;
using bf16x8 = __attribute__((ext_vector_type(8))) __bf16;

// ---------- helpers ----------
__device__ __forceinline__ unsigned short f2bf(float f) {
  unsigned int u = __builtin_bit_cast(unsigned int, f);
  u = (u + 0x7FFFu + ((u >> 16) & 1u)) >> 16;   // RNE
  return (unsigned short)u;
}

__device__ __forceinline__ void g2lds16(const void* g, void* l) {
  __builtin_amdgcn_global_load_lds(
      (const __attribute__((address_space(1))) void*)g,
      (__attribute__((address_space(3))) void*)l, 16, 0, 0);
}

// ---------- combined weight prep: W cast + A repack + B repack ----------
__global__ __launch_bounds__(256) void k_prep(const float* __restrict__ W,
                                              const float* __restrict__ A,
                                              const float* __restrict__ Bexp,
                                              unsigned short* __restrict__ Wb,
                                              unsigned short* __restrict__ Ab,
                                              unsigned short* __restrict__ Bb) {
  int b = blockIdx.x;
  if (b < 2048) {                       // W: (2048,2048) f32 -> bf16, 8/thread
    int t = b * 256 + threadIdx.x;
    const float4* p = (const float4*)W;
    float4 a = p[2 * t], c = p[2 * t + 1];
    uint4 o;
    o.x = (unsigned)f2bf(a.x) | ((unsigned)f2bf(a.y) << 16);
    o.y = (unsigned)f2bf(a.z) | ((unsigned)f2bf(a.w) << 16);
    o.z = (unsigned)f2bf(c.x) | ((unsigned)f2bf(c.y) << 16);
    o.w = (unsigned)f2bf(c.z) | ((unsigned)f2bf(c.w) << 16);
    ((uint4*)Wb)[t] = o;
  } else if (b < 3072) {                // A (E,D,R) -> Ab[j=e*16+r][d]
    int t = (b - 2048) * 256 + threadIdx.x;
    int j = t >> 11, d = t & 2047;
    Ab[t] = f2bf(A[((size_t)(j >> 4) * 2048 + d) * 16 + (j & 15)]);
  } else {                              // Bexp (E,R,O) -> Bb[o][j=e*16+r]
    int t = (b - 3072) * 256 + threadIdx.x;
    int j = t >> 11, o = t & 2047;
    Bb[(size_t)o * 128 + j] = f2bf(Bexp[(size_t)(j >> 4) * 32768 + (j & 15) * 2048 + o]);
  }
}

// ---------- router (f32 exact) fused with x -> bf16 cast ----------
__global__ __launch_bounds__(256) void k_router_cast(const float* __restrict__ x,
                                                     const float* __restrict__ Wr,
                                                     unsigned short* __restrict__ xb,
                                                     float* __restrict__ wout) {
  int tok  = blockIdx.x * 4 + (threadIdx.x >> 6);
  int lane = threadIdx.x & 63;
  const float4* xr = (const float4*)(x + (size_t)tok * 2048);
  float4 xv[8];
#pragma unroll
  for (int c = 0; c < 8; c++) xv[c] = xr[c * 64 + lane];
  uint2* xbr = (uint2*)(xb + (size_t)tok * 2048);
#pragma unroll
  for (int c = 0; c < 8; c++) {
    uint2 o;
    o.x = (unsigned)f2bf(xv[c].x) | ((unsigned)f2bf(xv[c].y) << 16);
    o.y = (unsigned)f2bf(xv[c].z) | ((unsigned)f2bf(xv[c].w) << 16);
    xbr[c * 64 + lane] = o;
  }
  float lg[8];
#pragma unroll
  for (int e = 0; e < 8; e++) {
    const float4* wr = (const float4*)(Wr + e * 2048);
    float p = 0.f;
#pragma unroll
    for (int c = 0; c < 8; c++) {
      float4 wv = wr[c * 64 + lane];
      p += xv[c].x * wv.x + xv[c].y * wv.y + xv[c].z * wv.z + xv[c].w * wv.w;
    }
#pragma unroll
    for (int off = 32; off; off >>= 1) p += __shfl_xor(p, off);
    lg[e] = p;
  }
  int i1 = 0;
#pragma unroll
  for (int e = 1; e < 8; e++) if (lg[e] > lg[i1]) i1 = e;
  int i2 = (i1 == 0) ? 1 : 0;
#pragma unroll
  for (int e = 0; e < 8; e++) { if (e == i1) continue; if (lg[e] > lg[i2]) i2 = e; }
  float e2 = expf(lg[i2] - lg[i1]);
  float den = 1.f + e2;
  if (lane < 8) wout[(size_t)tok * 8 + lane] =
      (lane == i1) ? (1.f / den) : ((lane == i2) ? (e2 / den) : 0.f);
}

// ---------- LoRA-down GEMM (64x128 tile, 128 blocks) ----------
__global__ __launch_bounds__(256) void k_gemm_lora(const unsigned short* __restrict__ xb,
                                                   const unsigned short* __restrict__ Ab,
                                                   const float* __restrict__ wrt,
                                                   unsigned short* __restrict__ tmat) {
  __shared__ unsigned short lsA[64 * 64];
  __shared__ unsigned short lsB[128 * 64];
  const int w = threadIdx.x >> 6, lane = threadIdx.x & 63;
  const int mBase = blockIdx.y * 64;
  const int wr = (w >> 1) * 32, wc = (w & 1) * 64;
  f32x4 z = {0.f, 0.f, 0.f, 0.f};
  f32x4 acc[2][4];
#pragma unroll
  for (int i = 0; i < 2; i++)
#pragma unroll
    for (int j = 0; j < 4; j++) acc[i][j] = z;

  for (int s = 0; s < 32; ++s) {
    int k0 = s * 64;
#pragma unroll
    for (int q = 0; q < 2; ++q) {            // A: 64 rows = 8 rowblks
      int rb = w * 2 + q;
      int r  = rb * 8 + (lane >> 3);
      int cg = (lane & 7) ^ (r & 7);
      g2lds16(xb + (size_t)(mBase + r) * 2048 + k0 + cg * 8, (char*)lsA + rb * 1024);
    }
#pragma unroll
    for (int q = 0; q < 4; ++q) {            // B: 128 rows = 16 rowblks
      int rb = w * 4 + q;
      int r  = rb * 8 + (lane >> 3);
      int cg = (lane & 7) ^ (r & 7);
      g2lds16(Ab + (size_t)r * 2048 + k0 + cg * 8, (char*)lsB + rb * 1024);
    }
    __syncthreads();
#pragma unroll
    for (int kk = 0; kk < 2; ++kk) {
      bf16x8 af[2], bv[4];
#pragma unroll
      for (int i = 0; i < 2; ++i) {
        int r = wr + i * 16 + (lane & 15);
        int c = (kk * 4 + (lane >> 4)) ^ (r & 7);
        af[i] = *(const bf16x8*)((const char*)lsA + r * 128 + c * 16);
      }
#pragma unroll
      for (int j = 0; j < 4; ++j) {
        int r = wc + j * 16 + (lane & 15);
        int c = (kk * 4 + (lane >> 4)) ^ (r & 7);
        bv[j] = *(const bf16x8*)((const char*)lsB + r * 128 + c * 16);
      }
#pragma unroll
      for (int i = 0; i < 2; ++i)
#pragma unroll
        for (int j = 0; j < 4; ++j)
          acc[i][j] = __builtin_amdgcn_mfma_f32_16x16x32_bf16(af[i], bv[j], acc[i][j], 0, 0, 0);
    }
    __syncthreads();
  }
#pragma unroll
  for (int j = 0; j < 4; ++j) {
    int jj = wc + j * 16 + (lane & 15);
    int e  = jj >> 4;
#pragma unroll
    for (int i = 0; i < 2; ++i) {
      int m0 = mBase + wr + i * 16 + (lane >> 4) * 4;
#pragma unroll
      for (int q = 0; q < 4; ++q) {
        int m = m0 + q;
        tmat[(size_t)m * 128 + jj] = f2bf(acc[i][j][q] * wrt[(size_t)m * 8 + e]);
      }
    }
  }
}

// ---------- main GEMM: 256x256, BK=32, 4-buf ring, 2 phases/tile, counted vmcnt ----------
// out = xb.Wb^T (K=2048, tiles 0..63) ++ tmat.Bb^T (K=128, tiles 64..67) + bias
#define BAR() do { __builtin_amdgcn_s_barrier(); __builtin_amdgcn_sched_barrier(0); } while (0)
#define MFMA16(IO)                                                                   \
  do {                                                                               \
    __builtin_amdgcn_s_setprio(1);                                                   \
    _Pragma("unroll")                                                                \
    for (int i_ = 0; i_ < 4; ++i_) {                                                 \
      _Pragma("unroll")                                                              \
      for (int j_ = 0; j_ < 4; ++j_)                                                 \
        acc[(IO) + i_][j_] =                                                         \
            __builtin_amdgcn_mfma_f32_16x16x32_bf16(af[i_], bv[j_], acc[(IO) + i_][j_], 0, 0, 0); \
    }                                                                                \
    __builtin_amdgcn_s_setprio(0);                                                   \
  } while (0)

__global__ __launch_bounds__(512, 2) void k_gemm_main(const unsigned short* __restrict__ xb,
                                                      const unsigned short* __restrict__ Wb,
                                                      const unsigned short* __restrict__ tm,
                                                      const unsigned short* __restrict__ Bb,
                                                      const float* __restrict__ bias,
                                                      float* __restrict__ out) {
  __shared__ unsigned short lds[65536];          // 128 KiB: A 4 bufs x16KB @0, B @64KB
  char* L = (char*)lds;
  const int tid = threadIdx.x, wid = tid >> 6, lane = tid & 63;
  const int wm = wid >> 2, wn = wid & 3;         // 2M x 4N waves; wave tile 128x64
  const int bid = blockIdx.x;
  const int s = (bid & 7) * 32 + (bid >> 3);     // XCD swizzle (256 = 8*32, bijective)
  const int mBase = (s >> 3) * 256;
  const int nBase = (s & 7) * 256;
  const int rl = lane & 15, kq = lane >> 4;
  // ds_read: rows of 64B (BK=32), 4 chunks, XOR (row>>1)&3 swizzle -> 0-conflict (R2-proven)
  const int cR   = (kq << 4) ^ (((rl >> 1) & 3) << 4);
  const int aRow = (wm * 128 + rl) * 64;
  const int bRow = (wn * 64 + rl) * 64;
  // staging: per op, wave covers 16 rows x 64B; 2 rounds x (A,B) per tile
  const int sRo = lane >> 2;                                   // row in 16-group
  const int sC  = (((lane & 3) ^ ((lane >> 3) & 3)) << 3);     // pre-swizzled src col (elems)

  auto stage2 = [&](int tau, int o) {
    if (tau >= 68) return;
    const unsigned short *pa, *pb; int ld, k0;
    if (tau < 64) { pa = xb; pb = Wb; ld = 2048; k0 = tau * 32; }
    else          { pa = tm; pb = Bb; ld = 128;  k0 = (tau - 64) * 32; }
    const int r   = o * 128 + wid * 16 + sRo;
    const int dst = (tau & 3) * 16384 + o * 8192 + wid * 1024;
    g2lds16(pa + (size_t)(mBase + r) * ld + k0 + sC, L + dst);
    g2lds16(pb + (size_t)(nBase + r) * ld + k0 + sC, L + 65536 + dst);
  };

  f32x4 z = {0.f, 0.f, 0.f, 0.f};
  f32x4 acc[8][4];
#pragma unroll
  for (int i = 0; i < 8; ++i)
#pragma unroll
    for (int j = 0; j < 4; ++j) acc[i][j] = z;

  stage2(0, 0); stage2(0, 1);
  stage2(1, 0); stage2(1, 1);
  stage2(2, 0); stage2(2, 1);                    // 12 ops in flight
  asm volatile("s_waitcnt vmcnt(8)" ::: "memory");   // tile 0 landed
  BAR();

  for (int t = 0; t < 68; ++t) {
    const char* bA = L + (t & 3) * 16384;
    const char* bB = L + 65536 + (t & 3) * 16384;
    bf16x8 af[4], bv[4];
    // ---- phase 0: read bv + af[0..3]; stage round 0 of tile t+3; MFMA acc[0..3]
#pragma unroll
    for (int j = 0; j < 4; ++j) bv[j] = *(const bf16x8*)(bB + bRow + j * 1024 + cR);
#pragma unroll
    for (int i = 0; i < 4; ++i) af[i] = *(const bf16x8*)(bA + aRow + i * 1024 + cR);
    stage2(t + 3, 0);
    BAR();
    MFMA16(0);
    BAR();
    // ---- phase 1: read af[4..7]; stage round 1; counted wait; MFMA acc[4..7]
#pragma unroll
    for (int i = 0; i < 4; ++i) af[i] = *(const bf16x8*)(bA + aRow + (4 + i) * 1024 + cR);
    stage2(t + 3, 1);
    {
      int rem = 67 - t;   // allowed outstanding = ops for tiles t+2,t+3 that exist
      if (rem >= 3)      asm volatile("s_waitcnt vmcnt(8)" ::: "memory");
      else if (rem == 2) asm volatile("s_waitcnt vmcnt(4)" ::: "memory");
      else               asm volatile("s_waitcnt vmcnt(0)" ::: "memory");
    }
    BAR();
    MFMA16(4);
    BAR();
  }

#pragma unroll
  for (int j = 0; j < 4; ++j) {
    int o = nBase + wn * 64 + j * 16 + rl;
    float bb = bias[o];
#pragma unroll
    for (int i = 0; i < 8; ++i) {
      int m0 = mBase + wm * 128 + i * 16 + kq * 4;
#pragma unroll
      for (int q = 0; q < 4; ++q)
        out[(size_t)(m0 + q) * 2048 + o] = acc[i][j][q] + bb;
    }
  }
}

extern "C" void kernel_launch(void* const* d_in, const int* in_sizes, int n_in,
                              void* d_out, int out_size, void* d_ws, size_t ws_size,
                              hipStream_t stream) {
  const float* x    = (const float*)d_in[0];   // (4,2048,2048)
  const float* W    = (const float*)d_in[1];   // (2048,2048)
  const float* bias = (const float*)d_in[2];   // (2048)
  const float* Wr   = (const float*)d_in[3];   // (8,2048)
  const float* A    = (const float*)d_in[4];   // (8,2048,16)
  const float* Bexp = (const float*)d_in[5];   // (8,16,2048)
  float* out = (float*)d_out;

  char* ws = (char*)d_ws;
  unsigned short* xb = (unsigned short*)(ws);                 // 33,554,432 B
  unsigned short* Wb = (unsigned short*)(ws + 33554432);      //  8,388,608 B
  unsigned short* Ab = (unsigned short*)(ws + 41943040);      //    524,288 B
  unsigned short* Bb = (unsigned short*)(ws + 42467328);      //    524,288 B
  unsigned short* tm = (unsigned short*)(ws + 42991616);      //  2,097,152 B
  float*          wr = (float*)(ws + 45088768);               //    262,144 B

  (void)in_sizes; (void)n_in; (void)out_size; (void)ws_size;

  k_prep       <<<dim3(4096), 256, 0, stream>>>(W, A, Bexp, Wb, Ab, Bb);
  k_router_cast<<<dim3(2048), 256, 0, stream>>>(x, Wr, xb, wr);
  k_gemm_lora  <<<dim3(1, 128), 256, 0, stream>>>(xb, Ab, wr, tm);
  k_gemm_main  <<<dim3(256), 512, 0, stream>>>(xb, Wb, tm, Bb, bias, out);
}

// Round 5
// 145.977 us; speedup vs baseline: 1.0184x; 1.0184x over previous
//
#include <hip/hip_runtime.h>

using f32x4  = __attribute__((ext_vector_type(4))) float;
using f32x16 = __attribute__((ext_vector_type(16))) float;
using bf16x8 = __attribute__((ext_vector_type(8))) __bf16;

// ---------- helpers ----------
__device__ __forceinline__ unsigned short f2bf(float f) {
  unsigned int u = __builtin_bit_cast(unsigned int, f);
  u = (u + 0x7FFFu + ((u >> 16) & 1u)) >> 16;   // RNE
  return (unsigned short)u;
}

__device__ __forceinline__ void g2lds16(const void* g, void* l) {
  __builtin_amdgcn_global_load_lds(
      (const __attribute__((address_space(1))) void*)g,
      (__attribute__((address_space(3))) void*)l, 16, 0, 0);
}

// ---------- combined weight prep: W cast + A repack + B repack ----------
__global__ __launch_bounds__(256) void k_prep(const float* __restrict__ W,
                                              const float* __restrict__ A,
                                              const float* __restrict__ Bexp,
                                              unsigned short* __restrict__ Wb,
                                              unsigned short* __restrict__ Ab,
                                              unsigned short* __restrict__ Bb) {
  int b = blockIdx.x;
  if (b < 2048) {                       // W: (2048,2048) f32 -> bf16, 8/thread
    int t = b * 256 + threadIdx.x;
    const float4* p = (const float4*)W;
    float4 a = p[2 * t], c = p[2 * t + 1];
    uint4 o;
    o.x = (unsigned)f2bf(a.x) | ((unsigned)f2bf(a.y) << 16);
    o.y = (unsigned)f2bf(a.z) | ((unsigned)f2bf(a.w) << 16);
    o.z = (unsigned)f2bf(c.x) | ((unsigned)f2bf(c.y) << 16);
    o.w = (unsigned)f2bf(c.z) | ((unsigned)f2bf(c.w) << 16);
    ((uint4*)Wb)[t] = o;
  } else if (b < 3072) {                // A (E,D,R) -> Ab[j=e*16+r][d]
    int t = (b - 2048) * 256 + threadIdx.x;
    int j = t >> 11, d = t & 2047;
    Ab[t] = f2bf(A[((size_t)(j >> 4) * 2048 + d) * 16 + (j & 15)]);
  } else {                              // Bexp (E,R,O) -> Bb[o][j=e*16+r]
    int t = (b - 3072) * 256 + threadIdx.x;
    int j = t >> 11, o = t & 2047;
    Bb[(size_t)o * 128 + j] = f2bf(Bexp[(size_t)(j >> 4) * 32768 + (j & 15) * 2048 + o]);
  }
}

// ---------- router (f32 exact) fused with x -> bf16 cast ----------
__global__ __launch_bounds__(256) void k_router_cast(const float* __restrict__ x,
                                                     const float* __restrict__ Wr,
                                                     unsigned short* __restrict__ xb,
                                                     float* __restrict__ wout) {
  int tok  = blockIdx.x * 4 + (threadIdx.x >> 6);
  int lane = threadIdx.x & 63;
  const float4* xr = (const float4*)(x + (size_t)tok * 2048);
  float4 xv[8];
#pragma unroll
  for (int c = 0; c < 8; c++) xv[c] = xr[c * 64 + lane];
  uint2* xbr = (uint2*)(xb + (size_t)tok * 2048);
#pragma unroll
  for (int c = 0; c < 8; c++) {
    uint2 o;
    o.x = (unsigned)f2bf(xv[c].x) | ((unsigned)f2bf(xv[c].y) << 16);
    o.y = (unsigned)f2bf(xv[c].z) | ((unsigned)f2bf(xv[c].w) << 16);
    xbr[c * 64 + lane] = o;
  }
  float lg[8];
#pragma unroll
  for (int e = 0; e < 8; e++) {
    const float4* wr = (const float4*)(Wr + e * 2048);
    float p = 0.f;
#pragma unroll
    for (int c = 0; c < 8; c++) {
      float4 wv = wr[c * 64 + lane];
      p += xv[c].x * wv.x + xv[c].y * wv.y + xv[c].z * wv.z + xv[c].w * wv.w;
    }
#pragma unroll
    for (int off = 32; off; off >>= 1) p += __shfl_xor(p, off);
    lg[e] = p;
  }
  int i1 = 0;
#pragma unroll
  for (int e = 1; e < 8; e++) if (lg[e] > lg[i1]) i1 = e;
  int i2 = (i1 == 0) ? 1 : 0;
#pragma unroll
  for (int e = 0; e < 8; e++) { if (e == i1) continue; if (lg[e] > lg[i2]) i2 = e; }
  float e2 = expf(lg[i2] - lg[i1]);
  float den = 1.f + e2;
  if (lane < 8) wout[(size_t)tok * 8 + lane] =
      (lane == i1) ? (1.f / den) : ((lane == i2) ? (e2 / den) : 0.f);
}

// ---------- LoRA-down GEMM (32x128 tile, 256 blocks) ----------
__global__ __launch_bounds__(256) void k_gemm_lora(const unsigned short* __restrict__ xb,
                                                   const unsigned short* __restrict__ Ab,
                                                   const float* __restrict__ wrt,
                                                   unsigned short* __restrict__ tmat) {
  __shared__ unsigned short lsA[32 * 64];
  __shared__ unsigned short lsB[128 * 64];
  const int w = threadIdx.x >> 6, lane = threadIdx.x & 63;
  const int mBase = blockIdx.y * 32;
  const int rl = lane & 15, kq = lane >> 4;
  f32x4 z = {0.f, 0.f, 0.f, 0.f};
  f32x4 acc[2][2];
#pragma unroll
  for (int i = 0; i < 2; i++)
#pragma unroll
    for (int j = 0; j < 2; j++) acc[i][j] = z;

  for (int s = 0; s < 32; ++s) {
    int k0 = s * 64;
    {                                         // A: 32 rows = 4 rowblks, 1/wave
      int r  = w * 8 + (lane >> 3);
      int cg = (lane & 7) ^ (r & 7);
      g2lds16(xb + (size_t)(mBase + r) * 2048 + k0 + cg * 8, (char*)lsA + w * 1024);
    }
#pragma unroll
    for (int q = 0; q < 4; ++q) {             // B: 128 rows = 16 rowblks, 4/wave
      int rb = w * 4 + q;
      int r  = rb * 8 + (lane >> 3);
      int cg = (lane & 7) ^ (r & 7);
      g2lds16(Ab + (size_t)r * 2048 + k0 + cg * 8, (char*)lsB + rb * 1024);
    }
    __syncthreads();
#pragma unroll
    for (int kk = 0; kk < 2; ++kk) {
      bf16x8 af[2], bv[2];
#pragma unroll
      for (int i = 0; i < 2; ++i) {
        int r = i * 16 + rl;
        int c = (kk * 4 + kq) ^ (r & 7);
        af[i] = *(const bf16x8*)((const char*)lsA + r * 128 + c * 16);
      }
#pragma unroll
      for (int j = 0; j < 2; ++j) {
        int r = w * 32 + j * 16 + rl;
        int c = (kk * 4 + kq) ^ (r & 7);
        bv[j] = *(const bf16x8*)((const char*)lsB + r * 128 + c * 16);
      }
#pragma unroll
      for (int i = 0; i < 2; ++i)
#pragma unroll
        for (int j = 0; j < 2; ++j)
          acc[i][j] = __builtin_amdgcn_mfma_f32_16x16x32_bf16(af[i], bv[j], acc[i][j], 0, 0, 0);
    }
    __syncthreads();
  }
#pragma unroll
  for (int j = 0; j < 2; ++j) {
    int jj = w * 32 + j * 16 + rl;
    int e  = jj >> 4;
#pragma unroll
    for (int i = 0; i < 2; ++i) {
      int m0 = mBase + i * 16 + kq * 4;
#pragma unroll
      for (int q = 0; q < 4; ++q) {
        int m = m0 + q;
        tmat[(size_t)m * 128 + jj] = f2bf(acc[i][j][q] * wrt[(size_t)m * 8 + e]);
      }
    }
  }
}

// ---------- main GEMM: 256x256, BK=32, 4-buf ring, 32x32x16 MFMA ----------
// out = xb.Wb^T (K=2048, tiles 0..63) ++ tmat.Bb^T (K=128, tiles 64..67) + bias
__global__ __launch_bounds__(512, 2) void k_gemm_main(const unsigned short* __restrict__ xb,
                                                      const unsigned short* __restrict__ Wb,
                                                      const unsigned short* __restrict__ tm,
                                                      const unsigned short* __restrict__ Bb,
                                                      const float* __restrict__ bias,
                                                      float* __restrict__ out) {
  __shared__ unsigned short lds[65536];          // 128 KiB: A 4 bufs x16KB @0, B @64KB
  char* L = (char*)lds;
  const int tid = threadIdx.x, wid = tid >> 6, lane = tid & 63;
  const int wm = wid >> 2, wn = wid & 3;         // 2M x 4N waves; wave tile 128x64
  const int bid = blockIdx.x;
  const int s = (bid & 7) * 32 + (bid >> 3);     // XCD swizzle (256 = 8*32, bijective)
  const int mBase = (s >> 3) * 256;
  const int nBase = (s & 7) * 256;
  const int l31 = lane & 31, hi = lane >> 5;
  // staging: per op, wave covers 16 rows x 64B; 2 rounds x (A,B) per tile
  const int sRo = lane >> 2;                                   // row in 16-group
  const int sC  = (((lane & 3) ^ ((lane >> 3) & 3)) << 3);     // pre-swizzled src col (elems)

  auto stageTile = [&](int tau) {
    if (tau >= 68) return;
    const unsigned short *pa, *pb; int ld, k0;
    if (tau < 64) { pa = xb; pb = Wb; ld = 2048; k0 = tau * 32; }
    else          { pa = tm; pb = Bb; ld = 128;  k0 = (tau - 64) * 32; }
#pragma unroll
    for (int o = 0; o < 2; ++o) {
      const int r   = o * 128 + wid * 16 + sRo;
      const int dst = (tau & 3) * 16384 + o * 8192 + wid * 1024;
      g2lds16(pa + (size_t)(mBase + r) * ld + k0 + sC, L + dst);
      g2lds16(pb + (size_t)(nBase + r) * ld + k0 + sC, L + 65536 + dst);
    }
  };

  // fragment addresses: row*64B + swizzled 16B chunk; chunk = (ks*2+hi) ^ ((row>>1)&3)
  int aOff[4][2], bOff[2][2];
#pragma unroll
  for (int mi = 0; mi < 4; ++mi)
#pragma unroll
    for (int ks = 0; ks < 2; ++ks) {
      int r = wm * 128 + mi * 32 + l31;
      aOff[mi][ks] = r * 64 + (((ks * 2 + hi) ^ ((r >> 1) & 3)) << 4);
    }
#pragma unroll
  for (int nj = 0; nj < 2; ++nj)
#pragma unroll
    for (int ks = 0; ks < 2; ++ks) {
      int r = wn * 64 + nj * 32 + l31;
      bOff[nj][ks] = r * 64 + (((ks * 2 + hi) ^ ((r >> 1) & 3)) << 4);
    }

  f32x16 acc[4][2];
#pragma unroll
  for (int i = 0; i < 4; ++i)
#pragma unroll
    for (int j = 0; j < 2; ++j)
#pragma unroll
      for (int q = 0; q < 16; ++q) acc[i][j][q] = 0.f;

  stageTile(0); stageTile(1); stageTile(2);      // 12 ops in flight

  for (int t = 0; t < 68; ++t) {
    int rem = 67 - t;
    __builtin_amdgcn_sched_barrier(0);
    if (rem >= 2)      asm volatile("s_waitcnt vmcnt(8)" ::: "memory");
    else if (rem == 1) asm volatile("s_waitcnt vmcnt(4)" ::: "memory");
    else               asm volatile("s_waitcnt vmcnt(0)" ::: "memory");
    __builtin_amdgcn_s_barrier();
    __builtin_amdgcn_sched_barrier(0);
    stageTile(t + 3);                            // writes buf (t-1)&3: readers done

    const char* bA = L + (t & 3) * 16384;
    const char* bB = L + 65536 + (t & 3) * 16384;
    bf16x8 af[4], bv[2];
    // ---- ks = 0
#pragma unroll
    for (int j = 0; j < 2; ++j) bv[j] = *(const bf16x8*)(bB + bOff[j][0]);
#pragma unroll
    for (int i = 0; i < 4; ++i) af[i] = *(const bf16x8*)(bA + aOff[i][0]);
    __builtin_amdgcn_s_setprio(1);
#pragma unroll
    for (int i = 0; i < 4; ++i)
#pragma unroll
      for (int j = 0; j < 2; ++j)
        acc[i][j] = __builtin_amdgcn_mfma_f32_32x32x16_bf16(af[i], bv[j], acc[i][j], 0, 0, 0);
    __builtin_amdgcn_s_setprio(0);
    // ---- ks = 1
#pragma unroll
    for (int j = 0; j < 2; ++j) bv[j] = *(const bf16x8*)(bB + bOff[j][1]);
#pragma unroll
    for (int i = 0; i < 4; ++i) af[i] = *(const bf16x8*)(bA + aOff[i][1]);
    __builtin_amdgcn_s_setprio(1);
#pragma unroll
    for (int i = 0; i < 4; ++i)
#pragma unroll
      for (int j = 0; j < 2; ++j)
        acc[i][j] = __builtin_amdgcn_mfma_f32_32x32x16_bf16(af[i], bv[j], acc[i][j], 0, 0, 0);
    __builtin_amdgcn_s_setprio(0);
  }

  // epilogue: C/D layout col=lane&31, row=(reg&3)+8*(reg>>2)+4*(lane>>5)
#pragma unroll
  for (int nj = 0; nj < 2; ++nj) {
    int o = nBase + wn * 64 + nj * 32 + l31;
    float bb = bias[o];
#pragma unroll
    for (int mi = 0; mi < 4; ++mi) {
      int mb = mBase + wm * 128 + mi * 32 + 4 * hi;
#pragma unroll
      for (int reg = 0; reg < 16; ++reg) {
        int row = mb + (reg & 3) + 8 * (reg >> 2);
        out[(size_t)row * 2048 + o] = acc[mi][nj][reg] + bb;
      }
    }
  }
}

extern "C" void kernel_launch(void* const* d_in, const int* in_sizes, int n_in,
                              void* d_out, int out_size, void* d_ws, size_t ws_size,
                              hipStream_t stream) {
  const float* x    = (const float*)d_in[0];   // (4,2048,2048)
  const float* W    = (const float*)d_in[1];   // (2048,2048)
  const float* bias = (const float*)d_in[2];   // (2048)
  const float* Wr   = (const float*)d_in[3];   // (8,2048)
  const float* A    = (const float*)d_in[4];   // (8,2048,16)
  const float* Bexp = (const float*)d_in[5];   // (8,16,2048)
  float* out = (float*)d_out;

  char* ws = (char*)d_ws;
  unsigned short* xb = (unsigned short*)(ws);                 // 33,554,432 B
  unsigned short* Wb = (unsigned short*)(ws + 33554432);      //  8,388,608 B
  unsigned short* Ab = (unsigned short*)(ws + 41943040);      //    524,288 B
  unsigned short* Bb = (unsigned short*)(ws + 42467328);      //    524,288 B
  unsigned short* tm = (unsigned short*)(ws + 42991616);      //  2,097,152 B
  float*          wr = (float*)(ws + 45088768);               //    262,144 B

  (void)in_sizes; (void)n_in; (void)out_size; (void)ws_size;

  k_prep       <<<dim3(4096), 256, 0, stream>>>(W, A, Bexp, Wb, Ab, Bb);
  k_router_cast<<<dim3(2048), 256, 0, stream>>>(x, Wr, xb, wr);
  k_gemm_lora  <<<dim3(1, 256), 256, 0, stream>>>(xb, Ab, wr, tm);
  k_gemm_main  <<<dim3(256), 512, 0, stream>>>(xb, Wb, tm, Bb, bias, out);
}

// Round 6
// 142.453 us; speedup vs baseline: 1.0436x; 1.0247x over previous
//
#include <hip/hip_runtime.h>

using f32x4  = __attribute__((ext_vector_type(4))) float;
using bf16x8 = __attribute__((ext_vector_type(8))) __bf16;

// ---------- helpers ----------
__device__ __forceinline__ unsigned short f2bf(float f) {
  unsigned int u = __builtin_bit_cast(unsigned int, f);
  u = (u + 0x7FFFu + ((u >> 16) & 1u)) >> 16;   // RNE
  return (unsigned short)u;
}

__device__ __forceinline__ void g2lds16(const void* g, void* l) {
  __builtin_amdgcn_global_load_lds(
      (const __attribute__((address_space(1))) void*)g,
      (__attribute__((address_space(3))) void*)l, 16, 0, 0);
}

// ---------- fused prep: W cast + A repack + B repack + router/x-cast ----------
__global__ __launch_bounds__(256) void k_pre(const float* __restrict__ W,
                                             const float* __restrict__ A,
                                             const float* __restrict__ Bexp,
                                             const float* __restrict__ x,
                                             const float* __restrict__ Wr,
                                             unsigned short* __restrict__ Wb,
                                             unsigned short* __restrict__ Ab,
                                             unsigned short* __restrict__ Bb,
                                             unsigned short* __restrict__ xb,
                                             float* __restrict__ wout) {
  int b = blockIdx.x;
  if (b < 2048) {                       // W: (2048,2048) f32 -> bf16, 8/thread
    int t = b * 256 + threadIdx.x;
    const float4* p = (const float4*)W;
    float4 a = p[2 * t], c = p[2 * t + 1];
    uint4 o;
    o.x = (unsigned)f2bf(a.x) | ((unsigned)f2bf(a.y) << 16);
    o.y = (unsigned)f2bf(a.z) | ((unsigned)f2bf(a.w) << 16);
    o.z = (unsigned)f2bf(c.x) | ((unsigned)f2bf(c.y) << 16);
    o.w = (unsigned)f2bf(c.z) | ((unsigned)f2bf(c.w) << 16);
    ((uint4*)Wb)[t] = o;
    return;
  }
  if (b < 3072) {                       // A (E,D,R) -> Ab[j=e*16+r][d]
    int t = (b - 2048) * 256 + threadIdx.x;
    int j = t >> 11, d = t & 2047;
    Ab[t] = f2bf(A[((size_t)(j >> 4) * 2048 + d) * 16 + (j & 15)]);
    return;
  }
  if (b < 4096) {                       // Bexp (E,R,O) -> Bb[o][j=e*16+r]
    int t = (b - 3072) * 256 + threadIdx.x;
    int j = t >> 11, o = t & 2047;
    Bb[(size_t)o * 128 + j] = f2bf(Bexp[(size_t)(j >> 4) * 32768 + (j & 15) * 2048 + o]);
    return;
  }
  // router (f32 exact) + x -> bf16 cast; 4 tokens/block
  int tok  = (b - 4096) * 4 + (threadIdx.x >> 6);
  int lane = threadIdx.x & 63;
  const float4* xr = (const float4*)(x + (size_t)tok * 2048);
  float4 xv[8];
#pragma unroll
  for (int c = 0; c < 8; c++) xv[c] = xr[c * 64 + lane];
  uint2* xbr = (uint2*)(xb + (size_t)tok * 2048);
#pragma unroll
  for (int c = 0; c < 8; c++) {
    uint2 o;
    o.x = (unsigned)f2bf(xv[c].x) | ((unsigned)f2bf(xv[c].y) << 16);
    o.y = (unsigned)f2bf(xv[c].z) | ((unsigned)f2bf(xv[c].w) << 16);
    xbr[c * 64 + lane] = o;
  }
  float lg[8];
#pragma unroll
  for (int e = 0; e < 8; e++) {
    const float4* wr = (const float4*)(Wr + e * 2048);
    float p = 0.f;
#pragma unroll
    for (int c = 0; c < 8; c++) {
      float4 wv = wr[c * 64 + lane];
      p += xv[c].x * wv.x + xv[c].y * wv.y + xv[c].z * wv.z + xv[c].w * wv.w;
    }
#pragma unroll
    for (int off = 32; off; off >>= 1) p += __shfl_xor(p, off);
    lg[e] = p;
  }
  int i1 = 0;
#pragma unroll
  for (int e = 1; e < 8; e++) if (lg[e] > lg[i1]) i1 = e;
  int i2 = (i1 == 0) ? 1 : 0;
#pragma unroll
  for (int e = 0; e < 8; e++) { if (e == i1) continue; if (lg[e] > lg[i2]) i2 = e; }
  float e2 = expf(lg[i2] - lg[i1]);
  float den = 1.f + e2;
  if (lane < 8) wout[(size_t)tok * 8 + lane] =
      (lane == i1) ? (1.f / den) : ((lane == i2) ? (e2 / den) : 0.f);
}

// ---------- LoRA-down GEMM (32x128 tile, 256 blocks) ----------
__global__ __launch_bounds__(256) void k_gemm_lora(const unsigned short* __restrict__ xb,
                                                   const unsigned short* __restrict__ Ab,
                                                   const float* __restrict__ wrt,
                                                   unsigned short* __restrict__ tmat) {
  __shared__ unsigned short lsA[32 * 64];
  __shared__ unsigned short lsB[128 * 64];
  const int w = threadIdx.x >> 6, lane = threadIdx.x & 63;
  const int mBase = blockIdx.y * 32;
  const int rl = lane & 15, kq = lane >> 4;
  f32x4 z = {0.f, 0.f, 0.f, 0.f};
  f32x4 acc[2][2];
#pragma unroll
  for (int i = 0; i < 2; i++)
#pragma unroll
    for (int j = 0; j < 2; j++) acc[i][j] = z;

  for (int s = 0; s < 32; ++s) {
    int k0 = s * 64;
    {                                         // A: 32 rows = 4 rowblks, 1/wave
      int r  = w * 8 + (lane >> 3);
      int cg = (lane & 7) ^ (r & 7);
      g2lds16(xb + (size_t)(mBase + r) * 2048 + k0 + cg * 8, (char*)lsA + w * 1024);
    }
#pragma unroll
    for (int q = 0; q < 4; ++q) {             // B: 128 rows = 16 rowblks, 4/wave
      int rb = w * 4 + q;
      int r  = rb * 8 + (lane >> 3);
      int cg = (lane & 7) ^ (r & 7);
      g2lds16(Ab + (size_t)r * 2048 + k0 + cg * 8, (char*)lsB + rb * 1024);
    }
    __syncthreads();
#pragma unroll
    for (int kk = 0; kk < 2; ++kk) {
      bf16x8 af[2], bv[2];
#pragma unroll
      for (int i = 0; i < 2; ++i) {
        int r = i * 16 + rl;
        int c = (kk * 4 + kq) ^ (r & 7);
        af[i] = *(const bf16x8*)((const char*)lsA + r * 128 + c * 16);
      }
#pragma unroll
      for (int j = 0; j < 2; ++j) {
        int r = w * 32 + j * 16 + rl;
        int c = (kk * 4 + kq) ^ (r & 7);
        bv[j] = *(const bf16x8*)((const char*)lsB + r * 128 + c * 16);
      }
#pragma unroll
      for (int i = 0; i < 2; ++i)
#pragma unroll
        for (int j = 0; j < 2; ++j)
          acc[i][j] = __builtin_amdgcn_mfma_f32_16x16x32_bf16(af[i], bv[j], acc[i][j], 0, 0, 0);
    }
    __syncthreads();
  }
#pragma unroll
  for (int j = 0; j < 2; ++j) {
    int jj = w * 32 + j * 16 + rl;
    int e  = jj >> 4;
#pragma unroll
    for (int i = 0; i < 2; ++i) {
      int m0 = mBase + i * 16 + kq * 4;
#pragma unroll
      for (int q = 0; q < 4; ++q) {
        int m = m0 + q;
        tmat[(size_t)m * 128 + jj] = f2bf(acc[i][j][q] * wrt[(size_t)m * 8 + e]);
      }
    }
  }
}

// ---------- main GEMM: 128x256 tile, BK=32, ring-3 LDS, 2 blocks/CU ----------
// out = xb.Wb^T (K=2048, tiles 0..63) ++ tmat.Bb^T (K=128, tiles 64..67) + bias
__global__ __launch_bounds__(256, 2) void k_gemm_main(const unsigned short* __restrict__ xb,
                                                      const unsigned short* __restrict__ Wb,
                                                      const unsigned short* __restrict__ tm,
                                                      const unsigned short* __restrict__ Bb,
                                                      const float* __restrict__ bias,
                                                      float* __restrict__ out) {
  __shared__ unsigned short lds[36864];          // 72 KiB: A 3 bufs x 8KB @0; B 3 x 16KB @24KB
  char* L = (char*)lds;
  const int tid = threadIdx.x, wid = tid >> 6, lane = tid & 63;
  const int wm = wid >> 1, wn = wid & 1;         // 2M x 2N waves; wave tile 64 x 128
  const int bid = blockIdx.x;
  const int s = (bid & 7) * 64 + (bid >> 3);     // XCD swizzle (512 = 8*64, bijective)
  const int mBase = (s >> 3) * 128;
  const int nBase = (s & 7) * 256;
  const int rl = lane & 15, kq = lane >> 4;
  // frag offsets: row*64B + chunk*16, chunk = kq ^ ((row>>1)&3)  [R2-proven 0-conflict]
  int aOff[4], bOff[8];
#pragma unroll
  for (int i = 0; i < 4; ++i) {
    int r = wm * 64 + i * 16 + rl;
    aOff[i] = r * 64 + ((kq ^ ((r >> 1) & 3)) << 4);
  }
#pragma unroll
  for (int j = 0; j < 8; ++j) {
    int r = wn * 128 + j * 16 + rl;
    bOff[j] = r * 64 + ((kq ^ ((r >> 1) & 3)) << 4);
  }
  // staging: op covers 64 rows x 64B via 256 threads x 16B; linear LDS dest
  const int sRo = tid >> 2;                                    // row within op
  const int sC  = (((tid & 3) ^ ((tid >> 3) & 3)) << 3);       // pre-swizzled src col (elems)

  auto stage = [&](int tau, int bufi) {
    if (tau >= 68) return;
    const unsigned short *pa, *pb; int ld, k0;
    if (tau < 64) { pa = xb; pb = Wb; ld = 2048; k0 = tau * 32; }
    else          { pa = tm; pb = Bb; ld = 128;  k0 = (tau - 64) * 32; }
#pragma unroll
    for (int o = 0; o < 2; ++o)                  // A: 128 rows
      g2lds16(pa + (size_t)(mBase + o * 64 + sRo) * ld + k0 + sC,
              L + bufi * 8192 + o * 4096 + wid * 1024);
#pragma unroll
    for (int o = 0; o < 4; ++o)                  // B: 256 rows
      g2lds16(pb + (size_t)(nBase + o * 64 + sRo) * ld + k0 + sC,
              L + 24576 + bufi * 16384 + o * 4096 + wid * 1024);
  };

  f32x4 z = {0.f, 0.f, 0.f, 0.f};
  f32x4 acc[4][8];
#pragma unroll
  for (int i = 0; i < 4; ++i)
#pragma unroll
    for (int j = 0; j < 8; ++j) acc[i][j] = z;

  stage(0, 0); stage(1, 1);                      // 12 ops in flight
  int bR = 0, bS = 2;                            // read buf, stage buf

  for (int t = 0; t < 68; ++t) {
    __builtin_amdgcn_sched_barrier(0);
    if (t <= 65) asm volatile("s_waitcnt vmcnt(6)" ::: "memory");   // tile t landed
    else         asm volatile("s_waitcnt vmcnt(0)" ::: "memory");
    __builtin_amdgcn_s_barrier();
    __builtin_amdgcn_sched_barrier(0);
    stage(t + 2, bS);                            // buf (t+2)%3 = (t-1)%3: readers done

    const char* bA = L + bR * 8192;
    const char* bB = L + 24576 + bR * 16384;
    bf16x8 af[4], bv[8];
#pragma unroll
    for (int j = 0; j < 8; ++j) bv[j] = *(const bf16x8*)(bB + bOff[j]);
#pragma unroll
    for (int i = 0; i < 4; ++i) af[i] = *(const bf16x8*)(bA + aOff[i]);
    __builtin_amdgcn_s_setprio(1);
#pragma unroll
    for (int i = 0; i < 4; ++i)
#pragma unroll
      for (int j = 0; j < 8; ++j)
        acc[i][j] = __builtin_amdgcn_mfma_f32_16x16x32_bf16(af[i], bv[j], acc[i][j], 0, 0, 0);
    __builtin_amdgcn_s_setprio(0);

    bR = (bR == 2) ? 0 : bR + 1;
    bS = (bS == 2) ? 0 : bS + 1;
  }

#pragma unroll
  for (int j = 0; j < 8; ++j) {
    int o = nBase + wn * 128 + j * 16 + rl;
    float bb = bias[o];
#pragma unroll
    for (int i = 0; i < 4; ++i) {
      int m0 = mBase + wm * 64 + i * 16 + kq * 4;
#pragma unroll
      for (int q = 0; q < 4; ++q)
        out[(size_t)(m0 + q) * 2048 + o] = acc[i][j][q] + bb;
    }
  }
}

extern "C" void kernel_launch(void* const* d_in, const int* in_sizes, int n_in,
                              void* d_out, int out_size, void* d_ws, size_t ws_size,
                              hipStream_t stream) {
  const float* x    = (const float*)d_in[0];   // (4,2048,2048)
  const float* W    = (const float*)d_in[1];   // (2048,2048)
  const float* bias = (const float*)d_in[2];   // (2048)
  const float* Wr   = (const float*)d_in[3];   // (8,2048)
  const float* A    = (const float*)d_in[4];   // (8,2048,16)
  const float* Bexp = (const float*)d_in[5];   // (8,16,2048)
  float* out = (float*)d_out;

  char* ws = (char*)d_ws;
  unsigned short* xb = (unsigned short*)(ws);                 // 33,554,432 B
  unsigned short* Wb = (unsigned short*)(ws + 33554432);      //  8,388,608 B
  unsigned short* Ab = (unsigned short*)(ws + 41943040);      //    524,288 B
  unsigned short* Bb = (unsigned short*)(ws + 42467328);      //    524,288 B
  unsigned short* tm = (unsigned short*)(ws + 42991616);      //  2,097,152 B
  float*          wr = (float*)(ws + 45088768);               //    262,144 B

  (void)in_sizes; (void)n_in; (void)out_size; (void)ws_size;

  k_pre       <<<dim3(6144), 256, 0, stream>>>(W, A, Bexp, x, Wr, Wb, Ab, Bb, xb, wr);
  k_gemm_lora <<<dim3(1, 256), 256, 0, stream>>>(xb, Ab, wr, tm);
  k_gemm_main <<<dim3(512), 256, 0, stream>>>(xb, Wb, tm, Bb, bias, out);
}

// Round 7
// 142.400 us; speedup vs baseline: 1.0439x; 1.0004x over previous
//
#include <hip/hip_runtime.h>

using f32x4  = __attribute__((ext_vector_type(4))) float;
using bf16x8 = __attribute__((ext_vector_type(8))) __bf16;

// ---------- helpers ----------
__device__ __forceinline__ unsigned short f2bf(float f) {
  unsigned int u = __builtin_bit_cast(unsigned int, f);
  u = (u + 0x7FFFu + ((u >> 16) & 1u)) >> 16;   // RNE
  return (unsigned short)u;
}

__device__ __forceinline__ void g2lds16(const void* g, void* l) {
  __builtin_amdgcn_global_load_lds(
      (const __attribute__((address_space(1))) void*)g,
      (__attribute__((address_space(3))) void*)l, 16, 0, 0);
}

// ---------- fused prep: W cast + A repack + B repack + router/x-cast ----------
__global__ __launch_bounds__(256) void k_pre(const float* __restrict__ W,
                                             const float* __restrict__ A,
                                             const float* __restrict__ Bexp,
                                             const float* __restrict__ x,
                                             const float* __restrict__ Wr,
                                             unsigned short* __restrict__ Wb,
                                             unsigned short* __restrict__ Ab,
                                             unsigned short* __restrict__ Bb,
                                             unsigned short* __restrict__ xb,
                                             float* __restrict__ wout) {
  int b = blockIdx.x;
  if (b < 2048) {                       // W: (2048,2048) f32 -> bf16, 8/thread
    int t = b * 256 + threadIdx.x;
    const float4* p = (const float4*)W;
    float4 a = p[2 * t], c = p[2 * t + 1];
    uint4 o;
    o.x = (unsigned)f2bf(a.x) | ((unsigned)f2bf(a.y) << 16);
    o.y = (unsigned)f2bf(a.z) | ((unsigned)f2bf(a.w) << 16);
    o.z = (unsigned)f2bf(c.x) | ((unsigned)f2bf(c.y) << 16);
    o.w = (unsigned)f2bf(c.z) | ((unsigned)f2bf(c.w) << 16);
    ((uint4*)Wb)[t] = o;
    return;
  }
  if (b < 3072) {                       // A (E,D,R) -> Ab[j=e*16+r][d]
    int t = (b - 2048) * 256 + threadIdx.x;
    int j = t >> 11, d = t & 2047;
    Ab[t] = f2bf(A[((size_t)(j >> 4) * 2048 + d) * 16 + (j & 15)]);
    return;
  }
  if (b < 4096) {                       // Bexp (E,R,O) -> Bb[o][j=e*16+r]
    int t = (b - 3072) * 256 + threadIdx.x;
    int j = t >> 11, o = t & 2047;
    Bb[(size_t)o * 128 + j] = f2bf(Bexp[(size_t)(j >> 4) * 32768 + (j & 15) * 2048 + o]);
    return;
  }
  // router (f32 exact) + x -> bf16 cast; 4 tokens/block
  int tok  = (b - 4096) * 4 + (threadIdx.x >> 6);
  int lane = threadIdx.x & 63;
  const float4* xr = (const float4*)(x + (size_t)tok * 2048);
  float4 xv[8];
#pragma unroll
  for (int c = 0; c < 8; c++) xv[c] = xr[c * 64 + lane];
  uint2* xbr = (uint2*)(xb + (size_t)tok * 2048);
#pragma unroll
  for (int c = 0; c < 8; c++) {
    uint2 o;
    o.x = (unsigned)f2bf(xv[c].x) | ((unsigned)f2bf(xv[c].y) << 16);
    o.y = (unsigned)f2bf(xv[c].z) | ((unsigned)f2bf(xv[c].w) << 16);
    xbr[c * 64 + lane] = o;
  }
  float lg[8];
#pragma unroll
  for (int e = 0; e < 8; e++) {
    const float4* wr = (const float4*)(Wr + e * 2048);
    float p = 0.f;
#pragma unroll
    for (int c = 0; c < 8; c++) {
      float4 wv = wr[c * 64 + lane];
      p += xv[c].x * wv.x + xv[c].y * wv.y + xv[c].z * wv.z + xv[c].w * wv.w;
    }
#pragma unroll
    for (int off = 32; off; off >>= 1) p += __shfl_xor(p, off);
    lg[e] = p;
  }
  int i1 = 0;
#pragma unroll
  for (int e = 1; e < 8; e++) if (lg[e] > lg[i1]) i1 = e;
  int i2 = (i1 == 0) ? 1 : 0;
#pragma unroll
  for (int e = 0; e < 8; e++) { if (e == i1) continue; if (lg[e] > lg[i2]) i2 = e; }
  float e2 = expf(lg[i2] - lg[i1]);
  float den = 1.f + e2;
  if (lane < 8) wout[(size_t)tok * 8 + lane] =
      (lane == i1) ? (1.f / den) : ((lane == i2) ? (e2 / den) : 0.f);
}

// ---------- LoRA-down GEMM (32x128 tile, 256 blocks, strength-reduced staging) ----------
__global__ __launch_bounds__(256) void k_gemm_lora(const unsigned short* __restrict__ xb,
                                                   const unsigned short* __restrict__ Ab,
                                                   const float* __restrict__ wrt,
                                                   unsigned short* __restrict__ tmat) {
  __shared__ unsigned short lsA[32 * 64];
  __shared__ unsigned short lsB[128 * 64];
  const int w = threadIdx.x >> 6, lane = threadIdx.x & 63;
  const int mBase = blockIdx.y * 32;
  const int rl = lane & 15, kq = lane >> 4;
  // precomputed staging pointers, advanced by 64 elems (128B) per K-step
  const unsigned short* aS;
  const unsigned short* bS[4];
  {
    int r  = w * 8 + (lane >> 3);
    int cg = (lane & 7) ^ (r & 7);
    aS = xb + (size_t)(mBase + r) * 2048 + cg * 8;
  }
#pragma unroll
  for (int q = 0; q < 4; ++q) {
    int r  = (w * 4 + q) * 8 + (lane >> 3);
    int cg = (lane & 7) ^ (r & 7);
    bS[q] = Ab + (size_t)r * 2048 + cg * 8;
  }
  f32x4 z = {0.f, 0.f, 0.f, 0.f};
  f32x4 acc[2][2];
#pragma unroll
  for (int i = 0; i < 2; i++)
#pragma unroll
    for (int j = 0; j < 2; j++) acc[i][j] = z;

  for (int s = 0; s < 32; ++s) {
    g2lds16(aS, (char*)lsA + w * 1024);
    aS += 64;
#pragma unroll
    for (int q = 0; q < 4; ++q) {
      g2lds16(bS[q], (char*)lsB + (w * 4 + q) * 1024);
      bS[q] += 64;
    }
    __syncthreads();
#pragma unroll
    for (int kk = 0; kk < 2; ++kk) {
      bf16x8 af[2], bv[2];
#pragma unroll
      for (int i = 0; i < 2; ++i) {
        int r = i * 16 + rl;
        int c = (kk * 4 + kq) ^ (r & 7);
        af[i] = *(const bf16x8*)((const char*)lsA + r * 128 + c * 16);
      }
#pragma unroll
      for (int j = 0; j < 2; ++j) {
        int r = w * 32 + j * 16 + rl;
        int c = (kk * 4 + kq) ^ (r & 7);
        bv[j] = *(const bf16x8*)((const char*)lsB + r * 128 + c * 16);
      }
#pragma unroll
      for (int i = 0; i < 2; ++i)
#pragma unroll
        for (int j = 0; j < 2; ++j)
          acc[i][j] = __builtin_amdgcn_mfma_f32_16x16x32_bf16(af[i], bv[j], acc[i][j], 0, 0, 0);
    }
    __syncthreads();
  }
#pragma unroll
  for (int j = 0; j < 2; ++j) {
    int jj = w * 32 + j * 16 + rl;
    int e  = jj >> 4;
#pragma unroll
    for (int i = 0; i < 2; ++i) {
      int m0 = mBase + i * 16 + kq * 4;
#pragma unroll
      for (int q = 0; q < 4; ++q) {
        int m = m0 + q;
        tmat[(size_t)m * 128 + jj] = f2bf(acc[i][j][q] * wrt[(size_t)m * 8 + e]);
      }
    }
  }
}

// ---------- main GEMM: 128x256 tile, BK=32, ring-3 LDS, 2 blocks/CU ----------
// out = xb.Wb^T (K=2048, tiles 0..63) ++ tmat.Bb^T (K=128, tiles 64..67) + bias
__global__ __launch_bounds__(256, 2) void k_gemm_main(const unsigned short* __restrict__ xb,
                                                      const unsigned short* __restrict__ Wb,
                                                      const unsigned short* __restrict__ tm,
                                                      const unsigned short* __restrict__ Bb,
                                                      const float* __restrict__ bias,
                                                      float* __restrict__ out) {
  __shared__ unsigned short lds[36864];          // 72 KiB: A 3 bufs x 8KB @0; B 3 x 16KB @24KB
  char* L = (char*)lds;
  const int tid = threadIdx.x, wid = tid >> 6, lane = tid & 63;
  const int wm = wid >> 1, wn = wid & 1;         // 2M x 2N waves; wave tile 64 x 128
  const int bid = blockIdx.x;
  const int s = (bid & 7) * 64 + (bid >> 3);     // XCD swizzle (512 = 8*64, bijective)
  const int mBase = (s >> 3) * 128;
  const int nBase = (s & 7) * 256;
  const int rl = lane & 15, kq = lane >> 4;
  // frag offsets: row*64B + chunk*16, chunk = kq ^ ((row>>1)&3)  [R2-proven 0-conflict]
  int aOff[4], bOff[8];
#pragma unroll
  for (int i = 0; i < 4; ++i) {
    int r = wm * 64 + i * 16 + rl;
    aOff[i] = r * 64 + ((kq ^ ((r >> 1) & 3)) << 4);
  }
#pragma unroll
  for (int j = 0; j < 8; ++j) {
    int r = wn * 128 + j * 16 + rl;
    bOff[j] = r * 64 + ((kq ^ ((r >> 1) & 3)) << 4);
  }
  // staging: op covers 64 rows x 64B via 256 threads x 16B; linear LDS dest
  const int sRo = tid >> 2;                                    // row within op
  const int sC  = (((tid & 3) ^ ((tid >> 3) & 3)) << 3);       // pre-swizzled src col (elems)

  // strength-reduced staging pointers (main K range), +32 elems per staged tile
  const unsigned short* aSrc[2];
  const unsigned short* bSrc[4];
#pragma unroll
  for (int o = 0; o < 2; ++o) aSrc[o] = xb + (size_t)(mBase + o * 64 + sRo) * 2048 + sC;
#pragma unroll
  for (int o = 0; o < 4; ++o) bSrc[o] = Wb + (size_t)(nBase + o * 64 + sRo) * 2048 + sC;

  auto stage = [&](int tau, int bufi) {
    if (tau >= 68) return;
    if (tau < 64) {
#pragma unroll
      for (int o = 0; o < 2; ++o) {
        g2lds16(aSrc[o], L + bufi * 8192 + o * 4096 + wid * 1024);
        aSrc[o] += 32;
      }
#pragma unroll
      for (int o = 0; o < 4; ++o) {
        g2lds16(bSrc[o], L + 24576 + bufi * 16384 + o * 4096 + wid * 1024);
        bSrc[o] += 32;
      }
    } else {                                     // K-extension: 4 cold iterations
      int k0 = (tau - 64) * 32;
#pragma unroll
      for (int o = 0; o < 2; ++o)
        g2lds16(tm + (size_t)(mBase + o * 64 + sRo) * 128 + k0 + sC,
                L + bufi * 8192 + o * 4096 + wid * 1024);
#pragma unroll
      for (int o = 0; o < 4; ++o)
        g2lds16(Bb + (size_t)(nBase + o * 64 + sRo) * 128 + k0 + sC,
                L + 24576 + bufi * 16384 + o * 4096 + wid * 1024);
    }
  };

  f32x4 z = {0.f, 0.f, 0.f, 0.f};
  f32x4 acc[4][8];
#pragma unroll
  for (int i = 0; i < 4; ++i)
#pragma unroll
    for (int j = 0; j < 8; ++j) acc[i][j] = z;

  stage(0, 0); stage(1, 1);                      // 12 ops in flight
  int bR = 0, bS = 2;                            // read buf, stage buf

  for (int t = 0; t < 68; ++t) {
    __builtin_amdgcn_sched_barrier(0);
    if (t <= 65) asm volatile("s_waitcnt vmcnt(6)" ::: "memory");   // tile t landed
    else         asm volatile("s_waitcnt vmcnt(0)" ::: "memory");
    __builtin_amdgcn_s_barrier();
    __builtin_amdgcn_sched_barrier(0);
    stage(t + 2, bS);                            // buf (t+2)%3 = (t-1)%3: readers done

    const char* bA = L + bR * 8192;
    const char* bB = L + 24576 + bR * 16384;
    bf16x8 af[4], bv[8];
#pragma unroll
    for (int j = 0; j < 8; ++j) bv[j] = *(const bf16x8*)(bB + bOff[j]);
#pragma unroll
    for (int i = 0; i < 4; ++i) af[i] = *(const bf16x8*)(bA + aOff[i]);
    __builtin_amdgcn_s_setprio(1);
#pragma unroll
    for (int i = 0; i < 4; ++i)
#pragma unroll
      for (int j = 0; j < 8; ++j)
        acc[i][j] = __builtin_amdgcn_mfma_f32_16x16x32_bf16(af[i], bv[j], acc[i][j], 0, 0, 0);
    __builtin_amdgcn_s_setprio(0);

    bR = (bR == 2) ? 0 : bR + 1;
    bS = (bS == 2) ? 0 : bS + 1;
  }

#pragma unroll
  for (int j = 0; j < 8; ++j) {
    int o = nBase + wn * 128 + j * 16 + rl;
    float bb = bias[o];
#pragma unroll
    for (int i = 0; i < 4; ++i) {
      int m0 = mBase + wm * 64 + i * 16 + kq * 4;
#pragma unroll
      for (int q = 0; q < 4; ++q)
        out[(size_t)(m0 + q) * 2048 + o] = acc[i][j][q] + bb;
    }
  }
}

extern "C" void kernel_launch(void* const* d_in, const int* in_sizes, int n_in,
                              void* d_out, int out_size, void* d_ws, size_t ws_size,
                              hipStream_t stream) {
  const float* x    = (const float*)d_in[0];   // (4,2048,2048)
  const float* W    = (const float*)d_in[1];   // (2048,2048)
  const float* bias = (const float*)d_in[2];   // (2048)
  const float* Wr   = (const float*)d_in[3];   // (8,2048)
  const float* A    = (const float*)d_in[4];   // (8,2048,16)
  const float* Bexp = (const float*)d_in[5];   // (8,16,2048)
  float* out = (float*)d_out;

  char* ws = (char*)d_ws;
  unsigned short* xb = (unsigned short*)(ws);                 // 33,554,432 B
  unsigned short* Wb = (unsigned short*)(ws + 33554432);      //  8,388,608 B
  unsigned short* Ab = (unsigned short*)(ws + 41943040);      //    524,288 B
  unsigned short* Bb = (unsigned short*)(ws + 42467328);      //    524,288 B
  unsigned short* tm = (unsigned short*)(ws + 42991616);      //  2,097,152 B
  float*          wr = (float*)(ws + 45088768);               //    262,144 B

  (void)in_sizes; (void)n_in; (void)out_size; (void)ws_size;

  k_pre       <<<dim3(6144), 256, 0, stream>>>(W, A, Bexp, x, Wr, Wb, Ab, Bb, xb, wr);
  k_gemm_lora <<<dim3(1, 256), 256, 0, stream>>>(xb, Ab, wr, tm);
  k_gemm_main <<<dim3(512), 256, 0, stream>>>(xb, Wb, tm, Bb, bias, out);
}